// Round 2
// baseline (183.325 us; speedup 1.0000x reference)
//
#include <hip/hip_runtime.h>
#include <hip/hip_bf16.h>
#include <math.h>

// Problem constants
#define BZ      64
#define NC      2048
#define HH      14
#define HW      196        // 14*14
#define NCLS    1000
#define SPLITS  8
#define CPB     (NC/SPLITS)   // 256 channels per block
#define CHN     16            // channels per chunk
#define NCHUNK  (CPB/CHN)     // 16
#define NCT     224           // compute threads: 16 cg * 14 j

// ws layout (floats) — unchanged from round 1 (k2/k3 depend on it)
#define CAM_OFF  0                                  // [64][8][3][196]
#define G_OFF    (BZ*SPLITS*3*HW)                   // [64][8][196]
#define S_OFF    (G_OFF + BZ*SPLITS*HW)             // [64][8][14]
#define TERM_OFF (S_OFF + BZ*SPLITS*HH)             // [64]

// ---------------------------------------------------------------------------
// Kernel 1 (redesigned): per (batch, split=256ch) block.
// Compute threads t<224 own (cg = t/14, j = t%14). Per 16-channel chunk a
// thread reads the 14-elem column v[m]=F[cg][m][j] ONCE (14 b32) and updates:
//   - Gram triangle  gacc[e] += v[m]*v[m']   (105 FMA)
//   - cam partials   camk[m] += w_k * v[m]   (42 FMA)
//   - row sums       sacc[m] += v[m]         (14 add)
// => every LDS byte read exactly once; 7.5x less LDS traffic than round 1.
// End-of-block: padded-stride LDS scratch reductions -> ws partials.
// ---------------------------------------------------------------------------
__global__ __launch_bounds__(256) void k_stage1(
    const float* __restrict__ F, const float* __restrict__ W,
    const int* __restrict__ idx, float* __restrict__ ws)
{
  __shared__ __align__(16) float Fs[2][CHN*HW];     // 2 x 3136 floats (25 KB)
  __shared__ __align__(16) float wls[3][CPB];       // 3 KB
  __shared__ __align__(16) float SC[35*225];        // 31.5 KB reduction scratch
  __shared__ float SCB[224];                        // second-level partials

  const int t = threadIdx.x;
  const int s = blockIdx.x;     // split
  const int b = blockIdx.y;     // batch
  const int cbase = s*CPB;

  const int i0 = idx[b*3+0], i1 = idx[b*3+1], i2 = idx[b*3+2];
  wls[0][t] = W[(size_t)i0*NC + cbase + t];
  wls[1][t] = W[(size_t)i1*NC + cbase + t];
  wls[2][t] = W[(size_t)i2*NC + cbase + t];

  const float* Fb = F + ((size_t)b*NC + cbase)*HW;

  const bool isC = (t < NCT);
  const int cg = t / 14;        // channel slot within chunk (0..15)
  const int jj = t % 14;        // column (0..13)

  // accumulators (compiler keeps in VGPRs: all indices constant-unrolled)
  float gacc[105];
  float cam0[14], cam1[14], cam2[14], sacc[14];
  #pragma unroll
  for (int e=0;e<105;e++) gacc[e]=0.f;
  #pragma unroll
  for (int m=0;m<14;m++){ cam0[m]=0.f; cam1[m]=0.f; cam2[m]=0.f; sacc[m]=0.f; }

  // staging: chunk = 16 ch * 196 = 784 float4, contiguous copy (196=49*4)
  float4 pre0, pre1, pre2, pre3;
  auto loadChunk = [&](int ch){
    const float4* src = (const float4*)Fb + (size_t)ch*784;
    pre0 = src[t]; pre1 = src[t+256]; pre2 = src[t+512];
    if (t < 16) pre3 = src[t+768];
  };
  auto storeChunk = [&](int bufi){
    float4* dst = (float4*)&Fs[bufi][0];
    dst[t]=pre0; dst[t+256]=pre1; dst[t+512]=pre2;
    if (t < 16) dst[t+768]=pre3;
  };

  loadChunk(0);
  storeChunk(0);
  __syncthreads();

  for (int ch = 0; ch < NCHUNK; ++ch){
    const int bufi = ch & 1;
    if (ch+1 < NCHUNK) loadChunk(ch+1);   // prefetch next slab into regs

    if (isC){
      const float w0 = wls[0][ch*CHN + cg];
      const float w1 = wls[1][ch*CHN + cg];
      const float w2 = wls[2][ch*CHN + cg];
      const float* base = &Fs[bufi][cg*HW + jj];
      float v[14];
      #pragma unroll
      for (int m=0;m<14;m++) v[m] = base[m*14];
      #pragma unroll
      for (int m=0;m<14;m++){
        sacc[m] += v[m];
        cam0[m] += w0*v[m];
        cam1[m] += w1*v[m];
        cam2[m] += w2*v[m];
      }
      int e=0;
      #pragma unroll
      for (int m=0;m<14;m++){
        #pragma unroll
        for (int mp=m;mp<14;mp++){ gacc[e] += v[m]*v[mp]; e++; }
      }
    }

    if (ch+1 < NCHUNK) storeChunk((ch+1)&1);
    __syncthreads();
  }

  // ---- block reductions via padded scratch ----
  const size_t pslot = (size_t)(b*SPLITS + s);

  // Gram: 3 rounds of 35 entries; scratch stride 225 (odd -> bank spread)
  #pragma unroll
  for (int r=0;r<3;r++){
    if (isC){
      #pragma unroll
      for (int el=0; el<35; el++) SC[el*225 + t] = gacc[r*35 + el];
    }
    __syncthreads();
    if (t < 210){
      const int el = t / 6, g = t % 6;
      const int start = g*38, len = (g==5)? 34 : 38;
      float a = 0.f;
      for (int i=0;i<len;i++) a += SC[el*225 + start + i];
      SCB[el*6 + g] = a;
    }
    __syncthreads();
    if (t < 35){
      float a = 0.f;
      #pragma unroll
      for (int g=0; g<6; g++) a += SCB[t*6 + g];
      // decode triangle entry e = r*35 + t -> (m, mp), m<=mp
      int e = r*35 + t, m = 0, rem = e;
      while (rem >= 14 - m){ rem -= 14 - m; m++; }
      int mp = m + rem;
      float* gb = ws + G_OFF + pslot*HW;
      gb[m*HH + mp] = a;
      if (mp > m) gb[mp*HH + m] = a;
    }
    __syncthreads();
  }

  // cam: 3 rounds (k=0..2); scratch [pixel][cg] stride 17
  #pragma unroll
  for (int k=0;k<3;k++){
    if (isC){
      #pragma unroll
      for (int m=0;m<14;m++)
        SC[(m*14 + jj)*17 + cg] = (k==0)? cam0[m] : (k==1)? cam1[m] : cam2[m];
    }
    __syncthreads();
    if (t < HW){
      float a = 0.f;
      #pragma unroll
      for (int i=0;i<16;i++) a += SC[t*17 + i];
      ws[CAM_OFF + pslot*3*HW + k*HW + t] = a;
    }
    __syncthreads();
  }

  // S: scratch [m][224] stride 225
  if (isC){
    #pragma unroll
    for (int m=0;m<14;m++) SC[m*225 + t] = sacc[m];
  }
  __syncthreads();
  if (t < NCT){
    const int m = t % 14, g = t / 14;     // g<16
    float a = 0.f;
    #pragma unroll
    for (int i=0;i<14;i++) a += SC[m*225 + g*14 + i];
    SCB[m*16 + g] = a;
  }
  __syncthreads();
  if (t < HH){
    float a = 0.f;
    #pragma unroll
    for (int g=0; g<16; g++) a += SCB[t*16 + g];
    ws[S_OFF + pslot*HH + t] = a;
  }
}

// ---------------------------------------------------------------------------
// block reduce: MODE 0=sum, 1=min, 2=max; result broadcast to all 256 threads
// ---------------------------------------------------------------------------
template<int MODE>
__device__ __forceinline__ float bred(float v, float* red){
  #pragma unroll
  for (int o=32;o>0;o>>=1){
    float u = __shfl_down(v, o, 64);
    if (MODE==0) v += u; else if (MODE==1) v = fminf(v,u); else v = fmaxf(v,u);
  }
  __syncthreads();
  if ((threadIdx.x & 63)==0) red[threadIdx.x>>6] = v;
  __syncthreads();
  float r = red[0];
  #pragma unroll
  for (int w=1;w<4;w++){
    float u = red[w];
    if (MODE==0) r += u; else if (MODE==1) r = fminf(r,u); else r = fmaxf(r,u);
  }
  return r;
}

// ---------------------------------------------------------------------------
// Kernel 2: per-batch — reduce partials, normalize cams, dst/ed1, quadratic
// forms for d01/d02, cross-entropy, per-batch term.  (unchanged, validated)
// ---------------------------------------------------------------------------
__global__ __launch_bounds__(256) void k_stage2(
    const float* __restrict__ pred, const int* __restrict__ cla,
    const float* __restrict__ seg, float* __restrict__ ws)
{
  const int t = threadIdx.x, b = blockIdx.x;
  __shared__ float cam[3][HW], Gm[HW], Sv[HH];
  __shared__ float D1[HW], D2[HW], EE[HW];
  __shared__ float rowv[HH], dc1[HH], dc2[HH];
  __shared__ float red[4];
  __shared__ float scal[6];

  // A: reduce split partials
  if (t < HW){
    for (int k=0;k<3;k++){
      float a=0.f;
      for (int s=0;s<SPLITS;s++)
        a += ws[CAM_OFF + ((size_t)(b*SPLITS+s)*3 + k)*HW + t];
      cam[k][t]=a;
    }
    float g=0.f;
    for (int s=0;s<SPLITS;s++) g += ws[G_OFF + (size_t)(b*SPLITS+s)*HW + t];
    Gm[t]=g;
  }
  if (t < HH){
    float a=0.f;
    for (int s=0;s<SPLITS;s++) a += ws[S_OFF + (size_t)(b*SPLITS+s)*HH + t];
    Sv[t]=a;
  }
  __syncthreads();

  // B: per-cam min/max
  for (int k=0;k<3;k++){
    float v = (t<HW)? cam[k][t] : 3.0e38f;
    float mn = bred<1>(v, red);
    v = (t<HW)? cam[k][t] : -3.0e38f;
    float mx = bred<2>(v, red);
    if (t==0){ scal[2*k]=mn; scal[2*k+1]=mx; }
  }
  __syncthreads();

  // C: normalize, dst, D, EE
  if (t < HW){
    float c0 = (cam[0][t]-scal[0]) / (scal[1]-scal[0]) * 255.0f;
    float c1 = (cam[1][t]-scal[2]) / (scal[3]-scal[2]) * 255.0f;
    float c2 = (cam[2][t]-scal[4]) / (scal[5]-scal[4]) * 255.0f;
    float dst = (c0 > 125.0f) ? 1.0f : 0.0f;
    D1[t] = c0 - c1; D2[t] = c0 - c2;
    float e = dst - seg[(size_t)b*HW + t] + 1e-6f;
    EE[t] = e*e;
  }
  __syncthreads();

  if (t < HH){
    float rs=0.f, d1=0.f, d2=0.f;
    #pragma unroll
    for (int j=0;j<HH;j++){
      rs += EE[t*HH+j];
      d1 += D1[j*HH+t];
      d2 += D2[j*HH+t];
    }
    rowv[t] = sqrtf(rs); dc1[t]=d1; dc2[t]=d2;
  }
  __syncthreads();

  // D: H[m,m'] * G[m,m'] summed
  float v1=0.f, v2=0.f;
  if (t < HW){
    int m = t/HH, mp = t%HH;
    float h1=0.f, h2=0.f;
    #pragma unroll
    for (int i=0;i<HH;i++){
      h1 += D1[i*HH+m]*D1[i*HH+mp];
      h2 += D2[i*HH+m]*D2[i*HH+mp];
    }
    v1 = h1*Gm[t]; v2 = h2*Gm[t];
  }
  float sx2_1 = bred<0>(v1, red);
  float sx2_2 = bred<0>(v2, red);

  // E: logsumexp cross-entropy
  const float* pb = pred + (size_t)b*NCLS;
  float mv = -3.0e38f;
  for (int i=t;i<NCLS;i+=256) mv = fmaxf(mv, pb[i]);
  mv = bred<2>(mv, red);
  float es = 0.f;
  for (int i=t;i<NCLS;i+=256) es += expf(pb[i]-mv);
  es = bred<0>(es, red);

  if (t==0){
    float lse = mv + logf(es);
    float ce  = lse - pb[cla[b]];
    float ed1 = 0.f;
    #pragma unroll
    for (int i=0;i<HH;i++) ed1 += rowv[i];
    ed1 *= (1.0f/14.0f);
    float sx1=0.f, sx2=0.f;
    #pragma unroll
    for (int m=0;m<HH;m++){ sx1 += dc1[m]*Sv[m]; sx2 += dc2[m]*Sv[m]; }
    const float NEPS2 = 401408.0f * 1e-12f;
    float d01 = sqrtf(sx2_1 + 2e-6f*sx1 + NEPS2) * (1.0f/2048.0f);
    float d02 = sqrtf(sx2_2 + 2e-6f*sx2 + NEPS2) * (1.0f/2048.0f);
    float term = ed1 + fmaxf(0.0f, 70.0f - d01 - d02) + ce;
    ws[TERM_OFF + b] = term;
  }
}

// ---------------------------------------------------------------------------
// Kernel 3: mean over 64 batch terms -> scalar
// ---------------------------------------------------------------------------
__global__ void k_stage3(const float* __restrict__ ws, float* __restrict__ out){
  float v = ws[TERM_OFF + threadIdx.x];
  #pragma unroll
  for (int o=32;o>0;o>>=1) v += __shfl_down(v, o, 64);
  if (threadIdx.x==0) out[0] = v * (1.0f/64.0f);
}

extern "C" void kernel_launch(void* const* d_in, const int* in_sizes, int n_in,
                              void* d_out, int out_size, void* d_ws, size_t ws_size,
                              hipStream_t stream) {
  const float* pred = (const float*)d_in[0];
  const int*   cla  = (const int*)  d_in[1];
  const float* seg  = (const float*)d_in[2];
  const float* F    = (const float*)d_in[3];
  const float* W    = (const float*)d_in[4];
  const int*   idx  = (const int*)  d_in[5];
  float* out = (float*)d_out;
  float* ws  = (float*)d_ws;

  dim3 g1(SPLITS, BZ);
  k_stage1<<<g1, 256, 0, stream>>>(F, W, idx, ws);
  k_stage2<<<BZ, 256, 0, stream>>>(pred, cla, seg, ws);
  k_stage3<<<1, 64, 0, stream>>>(ws, out);
}

// Round 3
// 181.110 us; speedup vs baseline: 1.0122x; 1.0122x over previous
//
#include <hip/hip_runtime.h>
#include <hip/hip_bf16.h>
#include <math.h>

// Problem constants
#define BZ      64
#define NC      2048
#define HH      14
#define HW      196        // 14*14
#define NCLS    1000
#define SPLITS  8
#define CPB     (NC/SPLITS)   // 256 channels per block
#define CHN     16            // channels per chunk
#define NCHUNK  (CPB/CHN)     // 16
#define NCT     224           // compute threads: 16 cg * 14 j

// ws layout (floats) — unchanged (k2/k3 depend on it)
#define CAM_OFF  0                                  // [64][8][3][196]
#define G_OFF    (BZ*SPLITS*3*HW)                   // [64][8][196]
#define S_OFF    (G_OFF + BZ*SPLITS*HW)             // [64][8][14]
#define TERM_OFF (S_OFF + BZ*SPLITS*HH)             // [64]

// async global->LDS, 16B per lane; LDS dest = wave-uniform base + lane*16
__device__ __forceinline__ void gl_lds16(const float4* g, float* l){
  __builtin_amdgcn_global_load_lds(
      (const __attribute__((address_space(1))) void*)g,
      (__attribute__((address_space(3))) void*)l, 16, 0, 0);
}

// ---------------------------------------------------------------------------
// Kernel 1: per (batch, split=256ch) block. Compute threads t<224 own
// (cg = t/14, j = t%14); per 16-channel chunk read column v[m]=F[cg][m][j]
// once and update Gram triangle (105), cam partials (3x14), row sums (14).
// Staging via global_load_lds (no VGPR round-trip), double-buffered.
// LDS: staging (2x3136 + wls 768) unioned with epilogue scratch (8099).
// ---------------------------------------------------------------------------
__global__ __launch_bounds__(256, 2) void k_stage1(
    const float* __restrict__ F, const float* __restrict__ W,
    const int* __restrict__ idx, float* __restrict__ ws)
{
  __shared__ __align__(16) float U[8112];   // 32.4 KB union
  float* const Fs0 = U;                     // 3136
  float* const Fs1 = U + 3136;              // 3136
  float* const wls = U + 6272;              // 3*256
  float* const SC  = U;                     // epilogue scratch 35*225
  float* const SCB = U + 7875;              // 224

  const int t = threadIdx.x;
  const int s = blockIdx.x;     // split
  const int b = blockIdx.y;     // batch
  const int cbase = s*CPB;

  const int i0 = idx[b*3+0], i1 = idx[b*3+1], i2 = idx[b*3+2];
  wls[0*CPB + t] = W[(size_t)i0*NC + cbase + t];
  wls[1*CPB + t] = W[(size_t)i1*NC + cbase + t];
  wls[2*CPB + t] = W[(size_t)i2*NC + cbase + t];

  const float* Fb = F + ((size_t)b*NC + cbase)*HW;
  const float4* Fb4 = (const float4*)Fb;

  const bool isC = (t < NCT);
  const int cg = t / 14;        // channel slot within chunk (0..15)
  const int jj = t % 14;        // column (0..13)
  const int wv = t >> 6;        // wave id (uniform in wave)

  // accumulators
  float gacc[105];
  float cam0[14], cam1[14], cam2[14], sacc[14];
  #pragma unroll
  for (int e=0;e<105;e++) gacc[e]=0.f;
  #pragma unroll
  for (int m=0;m<14;m++){ cam0[m]=0.f; cam1[m]=0.f; cam2[m]=0.f; sacc[m]=0.f; }

  // chunk = 784 float4 (16ch * 196 / 4), contiguous; 3 full wave-rounds + 16
  auto issue = [&](int ch, int bufi){
    const float4* src = Fb4 + (size_t)ch*784;
    float* dstBase = bufi ? Fs1 : Fs0;
    #pragma unroll
    for (int i=0;i<3;i++)
      gl_lds16(src + i*256 + t, dstBase + (i*256 + wv*64)*4);
    if (t < 16)
      gl_lds16(src + 768 + t, dstBase + 768*4);
  };

  issue(0, 0);
  __syncthreads();

  for (int ch = 0; ch < NCHUNK; ++ch){
    if (ch+1 < NCHUNK) issue(ch+1, (ch+1)&1);

    if (isC){
      const float* Fsb = (ch & 1) ? Fs1 : Fs0;
      const float w0 = wls[0*CPB + ch*CHN + cg];
      const float w1 = wls[1*CPB + ch*CHN + cg];
      const float w2 = wls[2*CPB + ch*CHN + cg];
      const float* base = Fsb + cg*HW + jj;
      float v[14];
      #pragma unroll
      for (int m=0;m<14;m++) v[m] = base[m*14];
      #pragma unroll
      for (int m=0;m<14;m++){
        sacc[m] += v[m];
        cam0[m] += w0*v[m];
        cam1[m] += w1*v[m];
        cam2[m] += w2*v[m];
      }
      int e=0;
      #pragma unroll
      for (int m=0;m<14;m++){
        #pragma unroll
        for (int mp=m;mp<14;mp++){ gacc[e] += v[m]*v[mp]; e++; }
      }
    }
    __syncthreads();
  }

  // ---- block reductions via padded scratch (same order as round 2) ----
  const size_t pslot = (size_t)(b*SPLITS + s);

  // Gram: 3 rounds of 35 entries; scratch stride 225
  #pragma unroll
  for (int r=0;r<3;r++){
    if (isC){
      #pragma unroll
      for (int el=0; el<35; el++) SC[el*225 + t] = gacc[r*35 + el];
    }
    __syncthreads();
    if (t < 210){
      const int el = t / 6, g = t % 6;
      const int start = g*38, len = (g==5)? 34 : 38;
      float a = 0.f;
      for (int i=0;i<len;i++) a += SC[el*225 + start + i];
      SCB[el*6 + g] = a;
    }
    __syncthreads();
    if (t < 35){
      float a = 0.f;
      #pragma unroll
      for (int g=0; g<6; g++) a += SCB[t*6 + g];
      int e = r*35 + t, m = 0, rem = e;
      while (rem >= 14 - m){ rem -= 14 - m; m++; }
      int mp = m + rem;
      float* gb = ws + G_OFF + pslot*HW;
      gb[m*HH + mp] = a;
      if (mp > m) gb[mp*HH + m] = a;
    }
    __syncthreads();
  }

  // cam: 3 rounds (k=0..2); scratch [pixel][cg] stride 17
  #pragma unroll
  for (int k=0;k<3;k++){
    if (isC){
      #pragma unroll
      for (int m=0;m<14;m++)
        SC[(m*14 + jj)*17 + cg] = (k==0)? cam0[m] : (k==1)? cam1[m] : cam2[m];
    }
    __syncthreads();
    if (t < HW){
      float a = 0.f;
      #pragma unroll
      for (int i=0;i<16;i++) a += SC[t*17 + i];
      ws[CAM_OFF + pslot*3*HW + k*HW + t] = a;
    }
    __syncthreads();
  }

  // S: scratch [m][224] stride 225
  if (isC){
    #pragma unroll
    for (int m=0;m<14;m++) SC[m*225 + t] = sacc[m];
  }
  __syncthreads();
  if (t < NCT){
    const int m = t % 14, g = t / 14;     // g<16
    float a = 0.f;
    #pragma unroll
    for (int i=0;i<14;i++) a += SC[m*225 + g*14 + i];
    SCB[m*16 + g] = a;
  }
  __syncthreads();
  if (t < HH){
    float a = 0.f;
    #pragma unroll
    for (int g=0; g<16; g++) a += SCB[t*16 + g];
    ws[S_OFF + pslot*HH + t] = a;
  }
}

// ---------------------------------------------------------------------------
// block reduce: MODE 0=sum, 1=min, 2=max; result broadcast to all 256 threads
// ---------------------------------------------------------------------------
template<int MODE>
__device__ __forceinline__ float bred(float v, float* red){
  #pragma unroll
  for (int o=32;o>0;o>>=1){
    float u = __shfl_down(v, o, 64);
    if (MODE==0) v += u; else if (MODE==1) v = fminf(v,u); else v = fmaxf(v,u);
  }
  __syncthreads();
  if ((threadIdx.x & 63)==0) red[threadIdx.x>>6] = v;
  __syncthreads();
  float r = red[0];
  #pragma unroll
  for (int w=1;w<4;w++){
    float u = red[w];
    if (MODE==0) r += u; else if (MODE==1) r = fminf(r,u); else r = fmaxf(r,u);
  }
  return r;
}

// ---------------------------------------------------------------------------
// Kernel 2: per-batch — reduce partials, normalize cams, dst/ed1, quadratic
// forms for d01/d02, cross-entropy, per-batch term.  (unchanged, validated)
// ---------------------------------------------------------------------------
__global__ __launch_bounds__(256) void k_stage2(
    const float* __restrict__ pred, const int* __restrict__ cla,
    const float* __restrict__ seg, float* __restrict__ ws)
{
  const int t = threadIdx.x, b = blockIdx.x;
  __shared__ float cam[3][HW], Gm[HW], Sv[HH];
  __shared__ float D1[HW], D2[HW], EE[HW];
  __shared__ float rowv[HH], dc1[HH], dc2[HH];
  __shared__ float red[4];
  __shared__ float scal[6];

  // A: reduce split partials
  if (t < HW){
    for (int k=0;k<3;k++){
      float a=0.f;
      for (int s=0;s<SPLITS;s++)
        a += ws[CAM_OFF + ((size_t)(b*SPLITS+s)*3 + k)*HW + t];
      cam[k][t]=a;
    }
    float g=0.f;
    for (int s=0;s<SPLITS;s++) g += ws[G_OFF + (size_t)(b*SPLITS+s)*HW + t];
    Gm[t]=g;
  }
  if (t < HH){
    float a=0.f;
    for (int s=0;s<SPLITS;s++) a += ws[S_OFF + (size_t)(b*SPLITS+s)*HH + t];
    Sv[t]=a;
  }
  __syncthreads();

  // B: per-cam min/max
  for (int k=0;k<3;k++){
    float v = (t<HW)? cam[k][t] : 3.0e38f;
    float mn = bred<1>(v, red);
    v = (t<HW)? cam[k][t] : -3.0e38f;
    float mx = bred<2>(v, red);
    if (t==0){ scal[2*k]=mn; scal[2*k+1]=mx; }
  }
  __syncthreads();

  // C: normalize, dst, D, EE
  if (t < HW){
    float c0 = (cam[0][t]-scal[0]) / (scal[1]-scal[0]) * 255.0f;
    float c1 = (cam[1][t]-scal[2]) / (scal[3]-scal[2]) * 255.0f;
    float c2 = (cam[2][t]-scal[4]) / (scal[5]-scal[4]) * 255.0f;
    float dst = (c0 > 125.0f) ? 1.0f : 0.0f;
    D1[t] = c0 - c1; D2[t] = c0 - c2;
    float e = dst - seg[(size_t)b*HW + t] + 1e-6f;
    EE[t] = e*e;
  }
  __syncthreads();

  if (t < HH){
    float rs=0.f, d1=0.f, d2=0.f;
    #pragma unroll
    for (int j=0;j<HH;j++){
      rs += EE[t*HH+j];
      d1 += D1[j*HH+t];
      d2 += D2[j*HH+t];
    }
    rowv[t] = sqrtf(rs); dc1[t]=d1; dc2[t]=d2;
  }
  __syncthreads();

  // D: H[m,m'] * G[m,m'] summed
  float v1=0.f, v2=0.f;
  if (t < HW){
    int m = t/HH, mp = t%HH;
    float h1=0.f, h2=0.f;
    #pragma unroll
    for (int i=0;i<HH;i++){
      h1 += D1[i*HH+m]*D1[i*HH+mp];
      h2 += D2[i*HH+m]*D2[i*HH+mp];
    }
    v1 = h1*Gm[t]; v2 = h2*Gm[t];
  }
  float sx2_1 = bred<0>(v1, red);
  float sx2_2 = bred<0>(v2, red);

  // E: logsumexp cross-entropy
  const float* pb = pred + (size_t)b*NCLS;
  float mv = -3.0e38f;
  for (int i=t;i<NCLS;i+=256) mv = fmaxf(mv, pb[i]);
  mv = bred<2>(mv, red);
  float es = 0.f;
  for (int i=t;i<NCLS;i+=256) es += expf(pb[i]-mv);
  es = bred<0>(es, red);

  if (t==0){
    float lse = mv + logf(es);
    float ce  = lse - pb[cla[b]];
    float ed1 = 0.f;
    #pragma unroll
    for (int i=0;i<HH;i++) ed1 += rowv[i];
    ed1 *= (1.0f/14.0f);
    float sx1=0.f, sx2=0.f;
    #pragma unroll
    for (int m=0;m<HH;m++){ sx1 += dc1[m]*Sv[m]; sx2 += dc2[m]*Sv[m]; }
    const float NEPS2 = 401408.0f * 1e-12f;
    float d01 = sqrtf(sx2_1 + 2e-6f*sx1 + NEPS2) * (1.0f/2048.0f);
    float d02 = sqrtf(sx2_2 + 2e-6f*sx2 + NEPS2) * (1.0f/2048.0f);
    float term = ed1 + fmaxf(0.0f, 70.0f - d01 - d02) + ce;
    ws[TERM_OFF + b] = term;
  }
}

// ---------------------------------------------------------------------------
// Kernel 3: mean over 64 batch terms -> scalar
// ---------------------------------------------------------------------------
__global__ void k_stage3(const float* __restrict__ ws, float* __restrict__ out){
  float v = ws[TERM_OFF + threadIdx.x];
  #pragma unroll
  for (int o=32;o>0;o>>=1) v += __shfl_down(v, o, 64);
  if (threadIdx.x==0) out[0] = v * (1.0f/64.0f);
}

extern "C" void kernel_launch(void* const* d_in, const int* in_sizes, int n_in,
                              void* d_out, int out_size, void* d_ws, size_t ws_size,
                              hipStream_t stream) {
  const float* pred = (const float*)d_in[0];
  const int*   cla  = (const int*)  d_in[1];
  const float* seg  = (const float*)d_in[2];
  const float* F    = (const float*)d_in[3];
  const float* W    = (const float*)d_in[4];
  const int*   idx  = (const int*)  d_in[5];
  float* out = (float*)d_out;
  float* ws  = (float*)d_ws;

  dim3 g1(SPLITS, BZ);
  k_stage1<<<g1, 256, 0, stream>>>(F, W, idx, ws);
  k_stage2<<<BZ, 256, 0, stream>>>(pred, cla, seg, ws);
  k_stage3<<<1, 64, 0, stream>>>(ws, out);
}